// Round 10
// baseline (325.013 us; speedup 1.0000x reference)
//
#include <hip/hip_runtime.h>
#include <hip/hip_bf16.h>

// CausalSelfAttention: B=2, T=2048, C=1024, H=16, HD=64
// fp32 I/O, bf16/f16 MFMA internals.
//
// Round 10: LDS-free split-K flash attention.
//   Wave w owns keys [w*16, w*16+16) of each 64-key tile -> all K/V reads are
//   wave-disjoint and go global->register (L2-resident via XCD swizzle).
//   S^T = K . Q^T (16x16x32 bf16); P = exp2(S^T) stays in regs (C-layout ==
//   B-layout of 16x16x16 f16); O^T_partial += V^T . P; l via ones-MFMA.
//   No barriers / no LDS in the kt loop. Per q-tile, partial O summed across
//   waves via a 3-barrier LDS tree (40 KB). (p, 31-p) pairing -> 33 uniform
//   tiles/block; 512 blocks, XCD-local bh.

typedef __attribute__((ext_vector_type(8))) __bf16 bf16x8;
typedef __attribute__((ext_vector_type(8))) short short8;
typedef __attribute__((ext_vector_type(4))) short short4v;
typedef __attribute__((ext_vector_type(4))) float floatx4;
typedef __attribute__((ext_vector_type(2))) __fp16 fp16x2;
typedef __attribute__((ext_vector_type(4))) _Float16 half4v;

__device__ __forceinline__ unsigned short f2b(float f) {   // RNE
    unsigned int x = __float_as_uint(f);
    x += 0x7fffu + ((x >> 16) & 1u);
    return (unsigned short)(x >> 16);
}
__device__ __forceinline__ half4v pack4h(float a, float b, float c, float d) {
    union { fp16x2 c2[2]; half4v h4; } u;
    u.c2[0] = __builtin_amdgcn_cvt_pkrtz(a, b);
    u.c2[1] = __builtin_amdgcn_cvt_pkrtz(c, d);
    return u.h4;
}
__device__ __forceinline__ void gld16(const void* g, void* l) {
    __builtin_amdgcn_global_load_lds((const __attribute__((address_space(1))) void*)g,
                                     (__attribute__((address_space(3))) void*)l, 16, 0, 0);
}

// ---------------------------------------------------------------- prep (fused)
__global__ __launch_bounds__(256) void prep_k(
    const float* __restrict__ x,  unsigned short* __restrict__ xb,
    const float* __restrict__ Wa, unsigned short* __restrict__ WTa,
    const float* __restrict__ Wp, unsigned short* __restrict__ WTp)
{
    __shared__ unsigned short tl[64][72];
    const int id = blockIdx.x, t = threadIdx.x;

    if (id < 2048) {
        int i = (id * 256 + t) << 3;
        const float4 a = *(const float4*)(x + i);
        const float4 b = *(const float4*)(x + i + 4);
        short8 v;
        v[0] = (short)f2b(a.x); v[1] = (short)f2b(a.y);
        v[2] = (short)f2b(a.z); v[3] = (short)f2b(a.w);
        v[4] = (short)f2b(b.x); v[5] = (short)f2b(b.y);
        v[6] = (short)f2b(b.z); v[7] = (short)f2b(b.w);
        *(short8*)(xb + i) = v;
        return;
    }

    const float* in;
    unsigned short* out;
    int R, Cc, bx, by;
    if (id < 2816) {
        in = Wa; out = WTa; R = 1024; Cc = 3072;
        bx = (id - 2048) % 48; by = (id - 2048) / 48;
    } else {
        in = Wp; out = WTp; R = 1024; Cc = 1024;
        bx = (id - 2816) % 16; by = (id - 2816) / 16;
    }
    const int r0 = by * 64, c0 = bx * 64;
#pragma unroll
    for (int it = 0; it < 2; ++it) {
        int idx = it * 256 + t, r = idx >> 3, c8 = (idx & 7) << 3;
        const float* p = in + (size_t)(r0 + r) * Cc + c0 + c8;
        const float4 a = *(const float4*)p;
        const float4 b = *(const float4*)(p + 4);
        tl[r][c8 + 0] = f2b(a.x); tl[r][c8 + 1] = f2b(a.y);
        tl[r][c8 + 2] = f2b(a.z); tl[r][c8 + 3] = f2b(a.w);
        tl[r][c8 + 4] = f2b(b.x); tl[r][c8 + 5] = f2b(b.y);
        tl[r][c8 + 6] = f2b(b.z); tl[r][c8 + 7] = f2b(b.w);
    }
    __syncthreads();
#pragma unroll
    for (int it = 0; it < 2; ++it) {
        int idx = it * 256 + t, rr = idx >> 3, c8 = (idx & 7) << 3;
        short8 v;
#pragma unroll
        for (int i = 0; i < 8; ++i) v[i] = (short)tl[c8 + i][rr];
        *(short8*)(out + (size_t)(c0 + rr) * R + r0 + c8) = v;
    }
}

// ---------------------------------------------------------------- QKV GEMM
// q (pre-scaled by 0.125*log2e), k: bf16 [B,H,T,HD]; v: fp16 [B,H,HD,T].
__global__ __launch_bounds__(256) void gemm_qkv(
    const unsigned short* __restrict__ A,     // xb [4096][1024]
    const unsigned short* __restrict__ BT,    // WTa [3072][1024]
    const float* __restrict__ bias,
    unsigned short* __restrict__ outqk,       // q at +0, k at +4194304
    unsigned short* __restrict__ outvt)       // f16 [B,H,HD,T]
{
    __shared__ __align__(16) unsigned short SM[2][2][128][32];  // 32 KB
    unsigned short* Esc = &SM[0][0][0][0];                      // overlay [128][72]

    const int t = threadIdx.x;
    const int w = t >> 6, lane = t & 63, l15 = lane & 15, quad = lane >> 4;
    const int wr = w >> 1, wc = w & 1;
    const int m0 = blockIdx.y * 128, n0 = blockIdx.x * 128;
    const int K = 1024;

    float bia[4];
#pragma unroll
    for (int j = 0; j < 4; ++j) bia[j] = bias[n0 + wc * 64 + j * 16 + l15];

    floatx4 acc[4][4];
#pragma unroll
    for (int i = 0; i < 4; ++i)
#pragma unroll
        for (int j = 0; j < 4; ++j) acc[i][j] = (floatx4)0.f;

    const int row_s = t >> 2, kg_s = (t & 3) << 3;
    const unsigned short* gA = A  + (size_t)(m0 + row_s) * K + kg_s;
    const unsigned short* gB = BT + (size_t)(n0 + row_s) * K + kg_s;
    const int ldst = (w * 64) * 8;

#pragma unroll
    for (int c = 0; c < 2; ++c) {
        gld16(gA + (size_t)c * 64 * K, &SM[0][0][0][0] + c * 2048 + ldst);
        gld16(gB + (size_t)c * 64 * K, &SM[0][1][0][0] + c * 2048 + ldst);
    }

    for (int it = 0; it < 32; ++it) {
        __syncthreads();
        const int cur = it & 1;
        if (it < 31) {
            const int k0 = (it + 1) * 32;
#pragma unroll
            for (int c = 0; c < 2; ++c) {
                gld16(gA + (size_t)c * 64 * K + k0, &SM[cur ^ 1][0][0][0] + c * 2048 + ldst);
                gld16(gB + (size_t)c * 64 * K + k0, &SM[cur ^ 1][1][0][0] + c * 2048 + ldst);
            }
        }
        bf16x8 af[4], bfr[4];
#pragma unroll
        for (int i = 0; i < 4; ++i) af[i] = *(const bf16x8*)&SM[cur][0][wr * 64 + i * 16 + l15][quad * 8];
#pragma unroll
        for (int j = 0; j < 4; ++j) bfr[j] = *(const bf16x8*)&SM[cur][1][wc * 64 + j * 16 + l15][quad * 8];
#pragma unroll
        for (int i = 0; i < 4; ++i)
#pragma unroll
            for (int j = 0; j < 4; ++j)
                acc[i][j] = __builtin_amdgcn_mfma_f32_16x16x32_bf16(af[i], bfr[j], acc[i][j], 0, 0, 0);
    }

    // rows (tokens): m0 + wr*64 + i*16 + quad*4 + r ; cols: n0 + wc*64 + j*16 + l15
    const int bb = m0 >> 11, tbase = m0 & 2047;
    if (n0 < 2048) {
        for (int cf = 0; cf < 2; ++cf) {
            const int fb = n0 + cf * 64;
            const int which = fb >> 10, h = (fb & 1023) >> 6;
            const float scl = (which == 0) ? 0.18033688011112042f : 1.0f;  // q pre-scale
            __syncthreads();
            if (wc == cf) {
#pragma unroll
                for (int i = 0; i < 4; ++i)
#pragma unroll
                    for (int j = 0; j < 4; ++j)
#pragma unroll
                        for (int r = 0; r < 4; ++r)
                            Esc[(wr * 64 + i * 16 + quad * 4 + r) * 72 + j * 16 + l15] =
                                f2b((acc[i][j][r] + bia[j]) * scl);
            }
            __syncthreads();
            const int row = t >> 1, co = (t & 1) << 5;
            const unsigned short* src = Esc + row * 72 + co;
            unsigned short* dst = outqk + (size_t)which * 4194304
                + (((size_t)(bb * 16 + h) * 2048 + tbase + row) * 64 + co);
#pragma unroll
            for (int u = 0; u < 4; ++u)
                *(short8*)(dst + u * 8) = *(const short8*)(src + u * 8);
        }
    } else {
        // v: fp16, chunk = 64-token half; Esc as [128 d][72]
        const int hb = (n0 & 1023) >> 6;
        for (int hf = 0; hf < 2; ++hf) {
            __syncthreads();
            if (wr == hf) {
#pragma unroll
                for (int i = 0; i < 4; ++i)
#pragma unroll
                    for (int j = 0; j < 4; ++j) {
                        half4v hp = pack4h(acc[i][j][0] + bia[j], acc[i][j][1] + bia[j],
                                           acc[i][j][2] + bia[j], acc[i][j][3] + bia[j]);
                        *(half4v*)&Esc[(wc * 64 + j * 16 + l15) * 72 + i * 16 + quad * 4] = hp;
                    }
            }
            __syncthreads();
            const int dl = t >> 1, co = (t & 1) << 5;
            const int h = hb + (dl >> 6), d = dl & 63;
            const unsigned short* src = Esc + dl * 72 + co;
            unsigned short* dst = outvt
                + (((size_t)(bb * 16 + h) * 64 + d) * 2048 + tbase + hf * 64 + co);
#pragma unroll
            for (int u = 0; u < 4; ++u)
                *(short8*)(dst + u * 8) = *(const short8*)(src + u * 8);
        }
    }
}

// ---------------------------------------------------------------- proj GEMM
__global__ __launch_bounds__(256) void gemm_proj(
    const unsigned short* __restrict__ A,     // y [4096][1024]
    const unsigned short* __restrict__ BT,    // WTp [1024][1024]
    const float* __restrict__ bias,
    float* __restrict__ outf)
{
    __shared__ __align__(16) unsigned short SM[2][2][128][32];  // 32 KB
    float* Ef = (float*)&SM[0][0][0][0];                        // overlay [32][132]

    const int t = threadIdx.x;
    const int w = t >> 6, lane = t & 63, l15 = lane & 15, quad = lane >> 4;
    const int wr = w >> 1, wc = w & 1;
    const int m0 = blockIdx.y * 128, n0 = blockIdx.x * 128;
    const int K = 1024, N = 1024;

    float bia[4];
#pragma unroll
    for (int j = 0; j < 4; ++j) bia[j] = bias[n0 + wc * 64 + j * 16 + l15];

    floatx4 acc[4][4];
#pragma unroll
    for (int i = 0; i < 4; ++i)
#pragma unroll
        for (int j = 0; j < 4; ++j) acc[i][j] = (floatx4)0.f;

    const int row_s = t >> 2, kg_s = (t & 3) << 3;
    const unsigned short* gA = A  + (size_t)(m0 + row_s) * K + kg_s;
    const unsigned short* gB = BT + (size_t)(n0 + row_s) * K + kg_s;
    const int ldst = (w * 64) * 8;

#pragma unroll
    for (int c = 0; c < 2; ++c) {
        gld16(gA + (size_t)c * 64 * K, &SM[0][0][0][0] + c * 2048 + ldst);
        gld16(gB + (size_t)c * 64 * K, &SM[0][1][0][0] + c * 2048 + ldst);
    }

    for (int it = 0; it < 32; ++it) {
        __syncthreads();
        const int cur = it & 1;
        if (it < 31) {
            const int k0 = (it + 1) * 32;
#pragma unroll
            for (int c = 0; c < 2; ++c) {
                gld16(gA + (size_t)c * 64 * K + k0, &SM[cur ^ 1][0][0][0] + c * 2048 + ldst);
                gld16(gB + (size_t)c * 64 * K + k0, &SM[cur ^ 1][1][0][0] + c * 2048 + ldst);
            }
        }
        bf16x8 af[4], bfr[4];
#pragma unroll
        for (int i = 0; i < 4; ++i) af[i] = *(const bf16x8*)&SM[cur][0][wr * 64 + i * 16 + l15][quad * 8];
#pragma unroll
        for (int j = 0; j < 4; ++j) bfr[j] = *(const bf16x8*)&SM[cur][1][wc * 64 + j * 16 + l15][quad * 8];
#pragma unroll
        for (int i = 0; i < 4; ++i)
#pragma unroll
            for (int j = 0; j < 4; ++j)
                acc[i][j] = __builtin_amdgcn_mfma_f32_16x16x32_bf16(af[i], bfr[j], acc[i][j], 0, 0, 0);
    }

    for (int qf = 0; qf < 4; ++qf) {
        __syncthreads();
        if (wr == (qf >> 1)) {
            const int ib = (qf & 1) * 2;
#pragma unroll
            for (int ii = 0; ii < 2; ++ii)
#pragma unroll
                for (int j = 0; j < 4; ++j)
#pragma unroll
                    for (int r = 0; r < 4; ++r)
                        Ef[(ii * 16 + quad * 4 + r) * 132 + wc * 64 + j * 16 + l15] =
                            acc[ib + ii][j][r] + bia[j];
        }
        __syncthreads();
        const int row = t >> 3, co = (t & 7) << 4;
        const float* src = Ef + row * 132 + co;
        float* dst = outf + (size_t)(m0 + qf * 32 + row) * N + n0 + co;
#pragma unroll
        for (int u = 0; u < 4; ++u)
            *(float4*)(dst + u * 4) = *(const float4*)(src + u * 4);
    }
}

// ---------------------------------------------------------------- attention
// q (pre-scaled), k: bf16 [B,H,T,HD]; vt: fp16 [B,H,HD,T]; y: bf16 [B,T,C].
// Block = (bh, 64-row q-tile pair). Wave w owns keys [w*16,w*16+16) per tile.
__global__ __launch_bounds__(256) void attn_k(
    const unsigned short* __restrict__ qg,
    const unsigned short* __restrict__ kg,
    const unsigned short* __restrict__ vt,
    unsigned short* __restrict__ y)
{
    __shared__ float Ored[2 * 5120];           // 40 KB reduction scratch

    const int t = threadIdx.x, w = t >> 6, lane = t & 63;
    const int l15 = lane & 15, quad = lane >> 4;
    const int id = blockIdx.x;
    const int bh = (id & 7) * 4 + ((id >> 3) & 3);   // XCD-local bh
    const int p = id >> 5;                           // 0..15
    const int b = bh >> 4, h = bh & 15;

    const half4v onesh = {(_Float16)1.f, (_Float16)1.f, (_Float16)1.f, (_Float16)1.f};
    const unsigned short* kwave = kg + (size_t)bh * 2048 * 64 + (w * 16 + l15) * 64;

#pragma unroll 1
    for (int hv = 0; hv < 2; ++hv) {
        const int qt = hv ? (31 - p) : p;
        const int qbase = qt * 64;

        // Q B-frags: n=q=l15 (per qb), k=d=kk*32+quad*8+j
        bf16x8 Qf[4][2];
#pragma unroll
        for (int qb = 0; qb < 4; ++qb) {
            const unsigned short* qrow =
                qg + ((size_t)bh * 2048 + qbase + qb * 16 + l15) * 64 + quad * 8;
            Qf[qb][0] = *(const bf16x8*)(qrow);
            Qf[qb][1] = *(const bf16x8*)(qrow + 32);
        }

        floatx4 OT[4][4];                      // [qb][jd]: d=jd*16+quad*4+r, q=qb*16+l15
        floatx4 lacc[4];
#pragma unroll
        for (int qb = 0; qb < 4; ++qb) {
            lacc[qb] = (floatx4)0.f;
#pragma unroll
            for (int jd = 0; jd < 4; ++jd) OT[qb][jd] = (floatx4)0.f;
        }

        // prologue loads: tile 0, wave's key slice (global -> regs)
        bf16x8 Kc[2];
        half4v Vc[4];
        {
            const unsigned short* kp = kwave;  // key row = w*16+l15
            Kc[0] = *(const bf16x8*)(kp + quad * 8);
            Kc[1] = *(const bf16x8*)(kp + 32 + quad * 8);
#pragma unroll
            for (int jd = 0; jd < 4; ++jd)
                Vc[jd] = *(const half4v*)(vt + ((size_t)bh * 64 + jd * 16 + l15) * 2048
                                          + w * 16 + quad * 4);
        }

#pragma unroll 1
        for (int kt = 0; kt <= qt; ++kt) {
            // prefetch next tile (clamped; redundant on last iter)
            const int knb = (kt < qt ? kt + 1 : qt) * 64;
            bf16x8 Kn[2];
            half4v Vn[4];
            {
                const unsigned short* kp = kwave + (size_t)knb * 64;
                Kn[0] = *(const bf16x8*)(kp + quad * 8);
                Kn[1] = *(const bf16x8*)(kp + 32 + quad * 8);
#pragma unroll
                for (int jd = 0; jd < 4; ++jd)
                    Vn[jd] = *(const half4v*)(vt + ((size_t)bh * 64 + jd * 16 + l15) * 2048
                                              + knb + w * 16 + quad * 4);
            }

            const bool diag = (kt == qt);
#pragma unroll
            for (int qb = 0; qb < 4; ++qb) {
                if (diag && qb < w) continue;          // 16x16 block fully above diagonal

                floatx4 st = (floatx4)0.f;
                st = __builtin_amdgcn_mfma_f32_16x16x32_bf16(Kc[0], Qf[qb][0], st, 0, 0, 0);
                st = __builtin_amdgcn_mfma_f32_16x16x32_bf16(Kc[1], Qf[qb][1], st, 0, 0, 0);

                float e[4];
                if (diag && qb == w) {
                    const int kl = quad * 4, ql = l15;  // within 16x16 block
#pragma unroll
                    for (int r = 0; r < 4; ++r)
                        e[r] = (kl + r > ql) ? 0.f : exp2f(st[r]);
                } else {
#pragma unroll
                    for (int r = 0; r < 4; ++r) e[r] = exp2f(st[r]);
                }
                half4v Pf = pack4h(e[0], e[1], e[2], e[3]);

                lacc[qb] = __builtin_amdgcn_mfma_f32_16x16x16f16(onesh, Pf, lacc[qb], 0, 0, 0);
#pragma unroll
                for (int jd = 0; jd < 4; ++jd)
                    OT[qb][jd] = __builtin_amdgcn_mfma_f32_16x16x16f16(Vc[jd], Pf, OT[qb][jd], 0, 0, 0);
            }

#pragma unroll
            for (int kk = 0; kk < 2; ++kk) Kc[kk] = Kn[kk];
#pragma unroll
            for (int jd = 0; jd < 4; ++jd) Vc[jd] = Vn[jd];
        }

        // ---- cross-wave reduction (rows: qb*5+jd, jd=4 holds lacc) ----
        __syncthreads();                                   // B1
        if (w >= 2) {
            float* s = Ored + (w - 2) * 5120;
#pragma unroll
            for (int qb = 0; qb < 4; ++qb) {
#pragma unroll
                for (int jd = 0; jd < 4; ++jd)
                    *(floatx4*)(s + ((qb * 5 + jd) * 64 + lane) * 4) = OT[qb][jd];
                *(floatx4*)(s + ((qb * 5 + 4) * 64 + lane) * 4) = lacc[qb];
            }
        }
        __syncthreads();                                   // B2
        if (w < 2) {
            const float* s = Ored + w * 5120;
#pragma unroll
            for (int qb = 0; qb < 4; ++qb) {
#pragma unroll
                for (int jd = 0; jd < 4; ++jd)
                    OT[qb][jd] += *(const floatx4*)(s + ((qb * 5 + jd) * 64 + lane) * 4);
                lacc[qb] += *(const floatx4*)(s + ((qb * 5 + 4) * 64 + lane) * 4);
            }
            // exchange: w0 -> slot0 qb{2,3}; w1 -> slot1 qb{0,1}
            float* d = Ored + w * 5120;
            const int qlo = (w == 0) ? 2 : 0;
#pragma unroll
            for (int q2 = 0; q2 < 2; ++q2) {
                const int qb = qlo + q2;
#pragma unroll
                for (int jd = 0; jd < 4; ++jd)
                    *(floatx4*)(d + ((qb * 5 + jd) * 64 + lane) * 4) = OT[qb][jd];
                *(floatx4*)(d + ((qb * 5 + 4) * 64 + lane) * 4) = lacc[qb];
            }
        }
        __syncthreads();                                   // B3
        if (w < 2) {
            const float* s = Ored + (1 - w) * 5120;
            const int qlo = (w == 0) ? 0 : 2;
#pragma unroll
            for (int q2 = 0; q2 < 2; ++q2) {
                const int qb = qlo + q2;
#pragma unroll
                for (int jd = 0; jd < 4; ++jd)
                    OT[qb][jd] += *(const floatx4*)(s + ((qb * 5 + jd) * 64 + lane) * 4);
                lacc[qb] += *(const floatx4*)(s + ((qb * 5 + 4) * 64 + lane) * 4);
                const float inv = 1.f / lacc[qb][0];
                const int q = qbase + qb * 16 + l15;
#pragma unroll
                for (int jd = 0; jd < 4; ++jd) {
                    short4v o;
#pragma unroll
                    for (int r = 0; r < 4; ++r) o[r] = (short)f2b(OT[qb][jd][r] * inv);
                    *(short4v*)(y + ((size_t)b * 2048 + q) * 1024 + h * 64 + jd * 16 + quad * 4) = o;
                }
            }
        }
    }
}

// ---------------------------------------------------------------- launcher
extern "C" void kernel_launch(void* const* d_in, const int* in_sizes, int n_in,
                              void* d_out, int out_size, void* d_ws, size_t ws_size,
                              hipStream_t stream) {
    const float* x      = (const float*)d_in[0];
    const float* W_attn = (const float*)d_in[1];
    const float* b_attn = (const float*)d_in[2];
    const float* W_proj = (const float*)d_in[3];
    const float* b_proj = (const float*)d_in[4];
    float* out = (float*)d_out;

    char* ws = (char*)d_ws;
    unsigned short* qk  = (unsigned short*)(ws);                    // q,k bf16 (16 MB)
    unsigned short* vtb = (unsigned short*)(ws + 16777216);         // v^T fp16 (8 MB)
    unsigned short* y   = (unsigned short*)(ws + 25165824);         // 8 MB
    unsigned short* xb  = (unsigned short*)(ws + 33554432);         // 8 MB
    unsigned short* WTa = (unsigned short*)(ws + 41943040);         // 6 MB
    unsigned short* WTp = (unsigned short*)(ws + 48234496);         // 2 MB

    prep_k<<<3072, 256, 0, stream>>>(x, xb, W_attn, WTa, W_proj, WTp);
    gemm_qkv<<<dim3(24, 32), 256, 0, stream>>>(xb, WTa, b_attn, qk, vtb);
    attn_k<<<512, 256, 0, stream>>>(qk, qk + 4194304, vtb, y);
    gemm_proj<<<dim3(8, 32), 256, 0, stream>>>(y, WTp, b_proj, out);
}

// Round 11
// 203.574 us; speedup vs baseline: 1.5965x; 1.5965x over previous
//
#include <hip/hip_runtime.h>
#include <hip/hip_bf16.h>

// CausalSelfAttention: B=2, T=2048, C=1024, H=16, HD=64
// fp32 I/O, bf16/f16 MFMA internals.
//
// Round 11: round-7 attn structure (64-q tiles, 16 q/wave, (p,31-p) pairing,
// K/V dbuf, XCD swizzle) + round-9's verified S^T math:
//   S^T = K.Q^T (16x16x32 bf16, K = A-frag from LDS, Q = B-frag in regs)
//   P = exp2(S^T) stays in REGISTERS (S^T C-layout == B-layout of 16x16x16 f16)
//   O^T += V^T.P (16x16x16 f16, V fp16 in LDS); l via ones-MFMA.
// No P LDS round-trip, no lgkmcnt(0) wave stall. ~60 VGPRs (no spills).

typedef __attribute__((ext_vector_type(8))) __bf16 bf16x8;
typedef __attribute__((ext_vector_type(8))) short short8;
typedef __attribute__((ext_vector_type(4))) short short4v;
typedef __attribute__((ext_vector_type(4))) float floatx4;
typedef __attribute__((ext_vector_type(2))) __fp16 fp16x2;
typedef __attribute__((ext_vector_type(4))) _Float16 half4v;

__device__ __forceinline__ unsigned short f2b(float f) {   // RNE
    unsigned int x = __float_as_uint(f);
    x += 0x7fffu + ((x >> 16) & 1u);
    return (unsigned short)(x >> 16);
}
__device__ __forceinline__ half4v pack4h(float a, float b, float c, float d) {
    union { fp16x2 c2[2]; half4v h4; } u;
    u.c2[0] = __builtin_amdgcn_cvt_pkrtz(a, b);
    u.c2[1] = __builtin_amdgcn_cvt_pkrtz(c, d);
    return u.h4;
}
__device__ __forceinline__ void gld16(const void* g, void* l) {
    __builtin_amdgcn_global_load_lds((const __attribute__((address_space(1))) void*)g,
                                     (__attribute__((address_space(3))) void*)l, 16, 0, 0);
}

// ---------------------------------------------------------------- prep (fused)
__global__ __launch_bounds__(256) void prep_k(
    const float* __restrict__ x,  unsigned short* __restrict__ xb,
    const float* __restrict__ Wa, unsigned short* __restrict__ WTa,
    const float* __restrict__ Wp, unsigned short* __restrict__ WTp)
{
    __shared__ unsigned short tl[64][72];
    const int id = blockIdx.x, t = threadIdx.x;

    if (id < 2048) {
        int i = (id * 256 + t) << 3;
        const float4 a = *(const float4*)(x + i);
        const float4 b = *(const float4*)(x + i + 4);
        short8 v;
        v[0] = (short)f2b(a.x); v[1] = (short)f2b(a.y);
        v[2] = (short)f2b(a.z); v[3] = (short)f2b(a.w);
        v[4] = (short)f2b(b.x); v[5] = (short)f2b(b.y);
        v[6] = (short)f2b(b.z); v[7] = (short)f2b(b.w);
        *(short8*)(xb + i) = v;
        return;
    }

    const float* in;
    unsigned short* out;
    int R, Cc, bx, by;
    if (id < 2816) {
        in = Wa; out = WTa; R = 1024; Cc = 3072;
        bx = (id - 2048) % 48; by = (id - 2048) / 48;
    } else {
        in = Wp; out = WTp; R = 1024; Cc = 1024;
        bx = (id - 2816) % 16; by = (id - 2816) / 16;
    }
    const int r0 = by * 64, c0 = bx * 64;
#pragma unroll
    for (int it = 0; it < 2; ++it) {
        int idx = it * 256 + t, r = idx >> 3, c8 = (idx & 7) << 3;
        const float* p = in + (size_t)(r0 + r) * Cc + c0 + c8;
        const float4 a = *(const float4*)p;
        const float4 b = *(const float4*)(p + 4);
        tl[r][c8 + 0] = f2b(a.x); tl[r][c8 + 1] = f2b(a.y);
        tl[r][c8 + 2] = f2b(a.z); tl[r][c8 + 3] = f2b(a.w);
        tl[r][c8 + 4] = f2b(b.x); tl[r][c8 + 5] = f2b(b.y);
        tl[r][c8 + 6] = f2b(b.z); tl[r][c8 + 7] = f2b(b.w);
    }
    __syncthreads();
#pragma unroll
    for (int it = 0; it < 2; ++it) {
        int idx = it * 256 + t, rr = idx >> 3, c8 = (idx & 7) << 3;
        short8 v;
#pragma unroll
        for (int i = 0; i < 8; ++i) v[i] = (short)tl[c8 + i][rr];
        *(short8*)(out + (size_t)(c0 + rr) * R + r0 + c8) = v;
    }
}

// ---------------------------------------------------------------- QKV GEMM
// q (pre-scaled by 0.125*log2e), k: bf16 [B,H,T,HD]; v: fp16 [B,H,HD,T].
__global__ __launch_bounds__(256) void gemm_qkv(
    const unsigned short* __restrict__ A,     // xb [4096][1024]
    const unsigned short* __restrict__ BT,    // WTa [3072][1024]
    const float* __restrict__ bias,
    unsigned short* __restrict__ outqk,       // q at +0, k at +4194304
    unsigned short* __restrict__ outvt)       // f16 [B,H,HD,T]
{
    __shared__ __align__(16) unsigned short SM[2][2][128][32];  // 32 KB
    unsigned short* Esc = &SM[0][0][0][0];                      // overlay [128][72]

    const int t = threadIdx.x;
    const int w = t >> 6, lane = t & 63, l15 = lane & 15, quad = lane >> 4;
    const int wr = w >> 1, wc = w & 1;
    const int m0 = blockIdx.y * 128, n0 = blockIdx.x * 128;
    const int K = 1024;

    float bia[4];
#pragma unroll
    for (int j = 0; j < 4; ++j) bia[j] = bias[n0 + wc * 64 + j * 16 + l15];

    floatx4 acc[4][4];
#pragma unroll
    for (int i = 0; i < 4; ++i)
#pragma unroll
        for (int j = 0; j < 4; ++j) acc[i][j] = (floatx4)0.f;

    const int row_s = t >> 2, kg_s = (t & 3) << 3;
    const unsigned short* gA = A  + (size_t)(m0 + row_s) * K + kg_s;
    const unsigned short* gB = BT + (size_t)(n0 + row_s) * K + kg_s;
    const int ldst = (w * 64) * 8;

#pragma unroll
    for (int c = 0; c < 2; ++c) {
        gld16(gA + (size_t)c * 64 * K, &SM[0][0][0][0] + c * 2048 + ldst);
        gld16(gB + (size_t)c * 64 * K, &SM[0][1][0][0] + c * 2048 + ldst);
    }

    for (int it = 0; it < 32; ++it) {
        __syncthreads();
        const int cur = it & 1;
        if (it < 31) {
            const int k0 = (it + 1) * 32;
#pragma unroll
            for (int c = 0; c < 2; ++c) {
                gld16(gA + (size_t)c * 64 * K + k0, &SM[cur ^ 1][0][0][0] + c * 2048 + ldst);
                gld16(gB + (size_t)c * 64 * K + k0, &SM[cur ^ 1][1][0][0] + c * 2048 + ldst);
            }
        }
        bf16x8 af[4], bfr[4];
#pragma unroll
        for (int i = 0; i < 4; ++i) af[i] = *(const bf16x8*)&SM[cur][0][wr * 64 + i * 16 + l15][quad * 8];
#pragma unroll
        for (int j = 0; j < 4; ++j) bfr[j] = *(const bf16x8*)&SM[cur][1][wc * 64 + j * 16 + l15][quad * 8];
#pragma unroll
        for (int i = 0; i < 4; ++i)
#pragma unroll
            for (int j = 0; j < 4; ++j)
                acc[i][j] = __builtin_amdgcn_mfma_f32_16x16x32_bf16(af[i], bfr[j], acc[i][j], 0, 0, 0);
    }

    // rows (tokens): m0 + wr*64 + i*16 + quad*4 + r ; cols: n0 + wc*64 + j*16 + l15
    const int bb = m0 >> 11, tbase = m0 & 2047;
    if (n0 < 2048) {
        for (int cf = 0; cf < 2; ++cf) {
            const int fb = n0 + cf * 64;
            const int which = fb >> 10, h = (fb & 1023) >> 6;
            const float scl = (which == 0) ? 0.18033688011112042f : 1.0f;  // q pre-scale
            __syncthreads();
            if (wc == cf) {
#pragma unroll
                for (int i = 0; i < 4; ++i)
#pragma unroll
                    for (int j = 0; j < 4; ++j)
#pragma unroll
                        for (int r = 0; r < 4; ++r)
                            Esc[(wr * 64 + i * 16 + quad * 4 + r) * 72 + j * 16 + l15] =
                                f2b((acc[i][j][r] + bia[j]) * scl);
            }
            __syncthreads();
            const int row = t >> 1, co = (t & 1) << 5;
            const unsigned short* src = Esc + row * 72 + co;
            unsigned short* dst = outqk + (size_t)which * 4194304
                + (((size_t)(bb * 16 + h) * 2048 + tbase + row) * 64 + co);
#pragma unroll
            for (int u = 0; u < 4; ++u)
                *(short8*)(dst + u * 8) = *(const short8*)(src + u * 8);
        }
    } else {
        // v: fp16, chunk = 64-token half; Esc as [128 d][72]
        const int hb = (n0 & 1023) >> 6;
        for (int hf = 0; hf < 2; ++hf) {
            __syncthreads();
            if (wr == hf) {
#pragma unroll
                for (int i = 0; i < 4; ++i)
#pragma unroll
                    for (int j = 0; j < 4; ++j) {
                        half4v hp = pack4h(acc[i][j][0] + bia[j], acc[i][j][1] + bia[j],
                                           acc[i][j][2] + bia[j], acc[i][j][3] + bia[j]);
                        *(half4v*)&Esc[(wc * 64 + j * 16 + l15) * 72 + i * 16 + quad * 4] = hp;
                    }
            }
            __syncthreads();
            const int dl = t >> 1, co = (t & 1) << 5;
            const int h = hb + (dl >> 6), d = dl & 63;
            const unsigned short* src = Esc + dl * 72 + co;
            unsigned short* dst = outvt
                + (((size_t)(bb * 16 + h) * 64 + d) * 2048 + tbase + hf * 64 + co);
#pragma unroll
            for (int u = 0; u < 4; ++u)
                *(short8*)(dst + u * 8) = *(const short8*)(src + u * 8);
        }
    }
}

// ---------------------------------------------------------------- proj GEMM
__global__ __launch_bounds__(256) void gemm_proj(
    const unsigned short* __restrict__ A,     // y [4096][1024]
    const unsigned short* __restrict__ BT,    // WTp [1024][1024]
    const float* __restrict__ bias,
    float* __restrict__ outf)
{
    __shared__ __align__(16) unsigned short SM[2][2][128][32];  // 32 KB
    float* Ef = (float*)&SM[0][0][0][0];                        // overlay [32][132]

    const int t = threadIdx.x;
    const int w = t >> 6, lane = t & 63, l15 = lane & 15, quad = lane >> 4;
    const int wr = w >> 1, wc = w & 1;
    const int m0 = blockIdx.y * 128, n0 = blockIdx.x * 128;
    const int K = 1024, N = 1024;

    float bia[4];
#pragma unroll
    for (int j = 0; j < 4; ++j) bia[j] = bias[n0 + wc * 64 + j * 16 + l15];

    floatx4 acc[4][4];
#pragma unroll
    for (int i = 0; i < 4; ++i)
#pragma unroll
        for (int j = 0; j < 4; ++j) acc[i][j] = (floatx4)0.f;

    const int row_s = t >> 2, kg_s = (t & 3) << 3;
    const unsigned short* gA = A  + (size_t)(m0 + row_s) * K + kg_s;
    const unsigned short* gB = BT + (size_t)(n0 + row_s) * K + kg_s;
    const int ldst = (w * 64) * 8;

#pragma unroll
    for (int c = 0; c < 2; ++c) {
        gld16(gA + (size_t)c * 64 * K, &SM[0][0][0][0] + c * 2048 + ldst);
        gld16(gB + (size_t)c * 64 * K, &SM[0][1][0][0] + c * 2048 + ldst);
    }

    for (int it = 0; it < 32; ++it) {
        __syncthreads();
        const int cur = it & 1;
        if (it < 31) {
            const int k0 = (it + 1) * 32;
#pragma unroll
            for (int c = 0; c < 2; ++c) {
                gld16(gA + (size_t)c * 64 * K + k0, &SM[cur ^ 1][0][0][0] + c * 2048 + ldst);
                gld16(gB + (size_t)c * 64 * K + k0, &SM[cur ^ 1][1][0][0] + c * 2048 + ldst);
            }
        }
        bf16x8 af[4], bfr[4];
#pragma unroll
        for (int i = 0; i < 4; ++i) af[i] = *(const bf16x8*)&SM[cur][0][wr * 64 + i * 16 + l15][quad * 8];
#pragma unroll
        for (int j = 0; j < 4; ++j) bfr[j] = *(const bf16x8*)&SM[cur][1][wc * 64 + j * 16 + l15][quad * 8];
#pragma unroll
        for (int i = 0; i < 4; ++i)
#pragma unroll
            for (int j = 0; j < 4; ++j)
                acc[i][j] = __builtin_amdgcn_mfma_f32_16x16x32_bf16(af[i], bfr[j], acc[i][j], 0, 0, 0);
    }

    for (int qf = 0; qf < 4; ++qf) {
        __syncthreads();
        if (wr == (qf >> 1)) {
            const int ib = (qf & 1) * 2;
#pragma unroll
            for (int ii = 0; ii < 2; ++ii)
#pragma unroll
                for (int j = 0; j < 4; ++j)
#pragma unroll
                    for (int r = 0; r < 4; ++r)
                        Ef[(ii * 16 + quad * 4 + r) * 132 + wc * 64 + j * 16 + l15] =
                            acc[ib + ii][j][r] + bia[j];
        }
        __syncthreads();
        const int row = t >> 3, co = (t & 7) << 4;
        const float* src = Ef + row * 132 + co;
        float* dst = outf + (size_t)(m0 + qf * 32 + row) * N + n0 + co;
#pragma unroll
        for (int u = 0; u < 4; ++u)
            *(float4*)(dst + u * 4) = *(const float4*)(src + u * 4);
    }
}

// ---------------------------------------------------------------- attention
// q (pre-scaled), k: bf16 [B,H,T,HD]; vt: fp16 [B,H,HD,T]; y: bf16 [B,T,C].
// One block = (b,h) x 64-q-tile pair (p, 31-p). Wave w owns q cols [w*16,w*16+16).
__global__ __launch_bounds__(256) void attn_k(
    const unsigned short* __restrict__ qg,
    const unsigned short* __restrict__ kg,
    const unsigned short* __restrict__ vt,
    unsigned short* __restrict__ y)
{
    __shared__ unsigned short Kb[2][64][64];   // bf16, XOR-swizzled granules
    __shared__ unsigned short Vb[2][64][64];   // fp16 [d][key], same swizzle

    const int t = threadIdx.x, w = t >> 6, lane = t & 63;
    const int l15 = lane & 15, quad = lane >> 4;
    const int id = blockIdx.x;
    const int bh = (id & 7) * 4 + ((id >> 3) & 3);   // XCD-local bh
    const int p = id >> 5;                           // 0..15
    const int b = bh >> 4, h = bh & 15;

    const half4v onesh = {(_Float16)1.f, (_Float16)1.f, (_Float16)1.f, (_Float16)1.f};
    const int r_s = t >> 3, g_s = t & 7;

#pragma unroll 1
    for (int hv = 0; hv < 2; ++hv) {
        const int qt = hv ? (31 - p) : p;
        const int qbase = qt * 64;

        // Q B-frags for S^T (16x16x32): n = q = l15 (this wave's col w*16+l15),
        // k = d = kk*32 + quad*8 + j  -- straight from global, stays in regs
        bf16x8 Qf[2];
        {
            const unsigned short* qrow =
                qg + ((size_t)bh * 2048 + qbase + w * 16 + l15) * 64 + quad * 8;
            Qf[0] = *(const bf16x8*)(qrow);
            Qf[1] = *(const bf16x8*)(qrow + 32);
        }

        floatx4 OT[4];                 // O^T: d = jd*16+quad*4+r, q = w*16+l15
        floatx4 lacc = (floatx4)0.f;
#pragma unroll
        for (int jd = 0; jd < 4; ++jd) OT[jd] = (floatx4)0.f;

        __syncthreads();               // prev half's LDS reads done
        // stage kt=0 into buf 0
#pragma unroll
        for (int c = 0; c < 2; ++c) {
            int r = c * 32 + r_s;
            int cg = (g_s ^ (r & 7)) << 3;
            gld16(kg + ((size_t)bh * 2048 + r) * 64 + cg,
                  &Kb[0][0][0] + (size_t)(c * 256 + w * 64) * 8);
            gld16(vt + ((size_t)bh * 64 + r) * 2048 + cg,
                  &Vb[0][0][0] + (size_t)(c * 256 + w * 64) * 8);
        }

#pragma unroll 1
        for (int kt = 0; kt <= qt; ++kt) {
            __syncthreads();           // drains loads into buf[cur]
            const int cur = kt & 1;
            if (kt < qt) {
                const int kbase = (kt + 1) * 64, nxt = cur ^ 1;
#pragma unroll
                for (int c = 0; c < 2; ++c) {
                    int r = c * 32 + r_s;
                    int cg = (g_s ^ (r & 7)) << 3;
                    gld16(kg + ((size_t)bh * 2048 + kbase + r) * 64 + cg,
                          &Kb[nxt][0][0] + (size_t)(c * 256 + w * 64) * 8);
                    gld16(vt + ((size_t)bh * 64 + r) * 2048 + kbase + cg,
                          &Vb[nxt][0][0] + (size_t)(c * 256 + w * 64) * 8);
                }
            }

            const bool diag = (kt == qt);
#pragma unroll
            for (int jk = 0; jk < 4; ++jk) {
                if (diag && jk > w) continue;          // block fully above diagonal

                // K A-frags: m = key = jk*16+l15, k = d = kk*32+quad*8+j
                bf16x8 Kf0 = *(const bf16x8*)&Kb[cur][jk * 16 + l15][((quad) ^ (l15 & 7)) << 3];
                bf16x8 Kf1 = *(const bf16x8*)&Kb[cur][jk * 16 + l15][((4 + quad) ^ (l15 & 7)) << 3];

                floatx4 st = (floatx4)0.f;
                st = __builtin_amdgcn_mfma_f32_16x16x32_bf16(Kf0, Qf[0], st, 0, 0, 0);
                st = __builtin_amdgcn_mfma_f32_16x16x32_bf16(Kf1, Qf[1], st, 0, 0, 0);

                // P = exp2(S^T); causal mask on the diagonal 16x16 block row
                float e[4];
                if (diag && jk == w) {
                    const int kl = jk * 16 + quad * 4, ql = w * 16 + l15;
#pragma unroll
                    for (int r = 0; r < 4; ++r)
                        e[r] = (kl + r > ql) ? 0.f : exp2f(st[r]);
                } else {
#pragma unroll
                    for (int r = 0; r < 4; ++r) e[r] = exp2f(st[r]);
                }
                half4v Pf = pack4h(e[0], e[1], e[2], e[3]);   // B-frag: k=quad*4+j, n=l15

                lacc = __builtin_amdgcn_mfma_f32_16x16x16f16(onesh, Pf, lacc, 0, 0, 0);
#pragma unroll
                for (int jd = 0; jd < 4; ++jd) {
                    // V^T A-frag: m = d = jd*16+l15, k = key = jk*16+quad*4+j
                    const int pc = (((2 * jk + (quad >> 1)) ^ (l15 & 7)) << 3) + (quad & 1) * 4;
                    half4v Vf = *(const half4v*)&Vb[cur][jd * 16 + l15][pc];
                    OT[jd] = __builtin_amdgcn_mfma_f32_16x16x16f16(Vf, Pf, OT[jd], 0, 0, 0);
                }
            }
        }

        // epilogue: q = qbase + w*16 + l15; d = jd*16 + quad*4 + r
        const float inv = 1.f / lacc[0];
        const int q = qbase + w * 16 + l15;
#pragma unroll
        for (int jd = 0; jd < 4; ++jd) {
            short4v o;
#pragma unroll
            for (int r = 0; r < 4; ++r) o[r] = (short)f2b(OT[jd][r] * inv);
            *(short4v*)(y + ((size_t)b * 2048 + q) * 1024 + h * 64 + jd * 16 + quad * 4) = o;
        }
    }
}

// ---------------------------------------------------------------- launcher
extern "C" void kernel_launch(void* const* d_in, const int* in_sizes, int n_in,
                              void* d_out, int out_size, void* d_ws, size_t ws_size,
                              hipStream_t stream) {
    const float* x      = (const float*)d_in[0];
    const float* W_attn = (const float*)d_in[1];
    const float* b_attn = (const float*)d_in[2];
    const float* W_proj = (const float*)d_in[3];
    const float* b_proj = (const float*)d_in[4];
    float* out = (float*)d_out;

    char* ws = (char*)d_ws;
    unsigned short* qk  = (unsigned short*)(ws);                    // q,k bf16 (16 MB)
    unsigned short* vtb = (unsigned short*)(ws + 16777216);         // v^T fp16 (8 MB)
    unsigned short* y   = (unsigned short*)(ws + 25165824);         // 8 MB
    unsigned short* xb  = (unsigned short*)(ws + 33554432);         // 8 MB
    unsigned short* WTa = (unsigned short*)(ws + 41943040);         // 6 MB
    unsigned short* WTp = (unsigned short*)(ws + 48234496);         // 2 MB

    prep_k<<<3072, 256, 0, stream>>>(x, xb, W_attn, WTa, W_proj, WTp);
    gemm_qkv<<<dim3(24, 32), 256, 0, stream>>>(xb, WTa, b_attn, qk, vtb);
    attn_k<<<512, 256, 0, stream>>>(qk, qk + 4194304, vtb, y);
    gemm_proj<<<dim3(8, 32), 256, 0, stream>>>(y, WTp, b_proj, out);
}